// Round 6
// baseline (387.109 us; speedup 1.0000x reference)
//
#include <hip/hip_runtime.h>
#include <stdint.h>

typedef short bf16x8 __attribute__((ext_vector_type(8)));
typedef float f32x4 __attribute__((ext_vector_type(4)));
typedef float f32x16 __attribute__((ext_vector_type(16)));
typedef unsigned short u16;
typedef unsigned int u32;

__device__ __forceinline__ u16 f2bf(float f) {
    u32 x = __float_as_uint(f);
    x += 0x7fffu + ((x >> 16) & 1u);
    return (u16)(x >> 16);
}
__device__ __forceinline__ u32 pack_bf2(float a, float b) {
    return (u32)f2bf(a) | ((u32)f2bf(b) << 16);
}

union Frag4 { u32 u[4]; bf16x8 v; };

// async global->LDS, 16B per lane; LDS dest is wave-uniform base + lane*16
__device__ __forceinline__ void gload16(const u16* g, u16* l) {
    __builtin_amdgcn_global_load_lds(
        (__attribute__((address_space(1))) void*)g,
        (__attribute__((address_space(3))) void*)l,
        16, 0, 0);
}

// ---------------- f32 -> bf16 cast, 8 elems/thread (G13: vectorized) --------
__global__ void cvt_f32_bf16(const float* __restrict__ in, u16* __restrict__ out, long n8) {
    long stride = (long)gridDim.x * blockDim.x;
    for (long i = (long)blockIdx.x * blockDim.x + threadIdx.x; i < n8; i += stride) {
        const float4* p = (const float4*)(in + i * 8);
        float4 a = p[0], b = p[1];
        uint4 o;
        o.x = pack_bf2(a.x, a.y);
        o.y = pack_bf2(a.z, a.w);
        o.z = pack_bf2(b.x, b.y);
        o.w = pack_bf2(b.z, b.w);
        ((uint4*)out)[i] = o;
    }
}

// ---------------- bf16 NT GEMM: out = A * B^T + bias ------------------------
// m97 structure: 128x128 tile, BK=64, 4 waves (2x2 of 64x64),
// global_load_lds width=16 staging with pre-swizzled source (rule #21),
// XOR-swizzled ds_read_b128, 2-barrier K-loop, XCD swizzle.
template<int OBF>
__global__ __launch_bounds__(256) void gemm_nt(
    const u16* __restrict__ A, const u16* __restrict__ B,
    const float* __restrict__ bias, void* __restrict__ out,
    int K, int ldo, int gxsh)
{
    __shared__ __align__(16) u16 lA[128 * 64];
    __shared__ __align__(16) u16 lB[128 * 64];
    const int tid  = threadIdx.x;
    const int lane = tid & 63;
    const int w    = tid >> 6;
    const int wm = (w >> 1) * 64, wn = (w & 1) * 64;

    const int nwg = gridDim.x;
    const int bid = blockIdx.x;
    const int swz = (bid & 7) * (nwg >> 3) + (bid >> 3);
    const int bm = (swz & ((1 << gxsh) - 1)) * 128;
    const int bn = (swz >> gxsh) * 128;

    const int lr = lane >> 3;                       // row within chunk
    const u32 sb = (u32)((lane & 7) * 16);          // stored byte-in-row

    f32x4 acc[4][4];
#pragma unroll
    for (int i = 0; i < 4; ++i)
#pragma unroll
        for (int j = 0; j < 4; ++j)
#pragma unroll
            for (int r = 0; r < 4; ++r) acc[i][j][r] = 0.f;

    for (int k0 = 0; k0 < K; k0 += 64) {
#pragma unroll
        for (int i = 0; i < 4; ++i) {
            const int c = w * 4 + i;               // wave-uniform chunk id
            const int row = c * 8 + lr;
            const u32 col = (sb ^ ((u32)(row & 7) << 4)) >> 1;   // elems
            gload16(A + (size_t)(bm + row) * K + k0 + col, lA + c * 512);
            gload16(B + (size_t)(bn + row) * K + k0 + col, lB + c * 512);
        }
        __syncthreads();
#pragma unroll
        for (int kk = 0; kk < 2; ++kk) {
            bf16x8 af[4], bfr[4];
#pragma unroll
            for (int f = 0; f < 4; ++f) {
                const int m = wm + f * 16 + (lane & 15);
                const u32 byt = (u32)(kk * 64 + (lane >> 4) * 16) ^ ((u32)(m & 7) << 4);
                af[f]  = *(const bf16x8*)((const char*)lA + m * 128 + byt);
                const int n = wn + f * 16 + (lane & 15);
                const u32 bytb = (u32)(kk * 64 + (lane >> 4) * 16) ^ ((u32)(n & 7) << 4);
                bfr[f] = *(const bf16x8*)((const char*)lB + n * 128 + bytb);
            }
#pragma unroll
            for (int i = 0; i < 4; ++i)
#pragma unroll
                for (int j = 0; j < 4; ++j)
                    acc[i][j] = __builtin_amdgcn_mfma_f32_16x16x32_bf16(af[i], bfr[j], acc[i][j], 0, 0, 0);
        }
        __syncthreads();
    }
#pragma unroll
    for (int i = 0; i < 4; ++i) {
        int m0 = bm + wm + i * 16 + ((lane >> 4) << 2);
#pragma unroll
        for (int j = 0; j < 4; ++j) {
            int n = bn + wn + j * 16 + (lane & 15);
            float bv = bias[n];
#pragma unroll
            for (int r = 0; r < 4; ++r) {
                float v = acc[i][j][r] + bv;
                if constexpr (OBF != 0)
                    ((u16*)out)[(size_t)(m0 + r) * ldo + n] = f2bf(v);
                else
                    ((float*)out)[(size_t)(m0 + r) * ldo + n] = v;
            }
        }
    }
}

// ---------------- V transpose: vt[b,h,d,t] <- qkv[b*2048+t][4096+h*128+d] ---
__global__ __launch_bounds__(256) void transpose_v(
    const u16* __restrict__ qkv, u16* __restrict__ vt)
{
    __shared__ u16 lt[64 * 64];   // rows of 128B, slot XOR-swizzled
    const int tid = threadIdx.x;
    const int bid = blockIdx.x;
    const int tt    = bid & 31;
    const int dtile = (bid >> 5) & 1;
    const int h     = (bid >> 6) & 15;
    const int b     = bid >> 10;
    const u16* src = qkv + ((size_t)b * 2048 + tt * 64) * 6144 + 4096 + h * 128 + dtile * 64;

    const int r = tid >> 2, ce = (tid & 3) * 16;   // row t, elem col in tile
    uint4 a0 = *(const uint4*)(src + (size_t)r * 6144 + ce);
    uint4 a1 = *(const uint4*)(src + (size_t)r * 6144 + ce + 8);
    const u32 swz = (u32)((r & 7) << 4);
    *(uint4*)((char*)lt + r * 128 + (((u32)(ce * 2)) ^ swz)) = a0;
    *(uint4*)((char*)lt + r * 128 + (((u32)(ce * 2 + 16)) ^ swz)) = a1;
    __syncthreads();

    const int d = tid >> 2;
    u16* dst = vt + ((size_t)(b * 16 + h) * 128 + dtile * 64 + d) * 2048 + tt * 64;
#pragma unroll
    for (int it = 0; it < 2; ++it) {
        const int t0 = (tid & 3) * 8 + it * 32;
        union { u16 hh[8]; uint4 q4; } u;
#pragma unroll
        for (int uu = 0; uu < 8; ++uu) {
            int trow = t0 + uu;
            u32 byt = (u32)(trow * 128) + (((u32)(d * 2)) ^ ((u32)((trow & 7) << 4)));
            u.hh[uu] = *(const u16*)((const char*)lt + byt);
        }
        *(uint4*)(dst + t0) = u.q4;
    }
}

// ---------------- causal flash attention ------------------------------------
// Block = (b, h, 128 q rows); 4 waves x 32 q rows. KVBLK=64 double-buffered.
// Merged-subtile softmax (one pass over 64 kv). No per-tile cross-half
// reduces: defer-max check rides __all (spans both halves); l_run kept as
// per-lane partial, merged once at the end. P^T exchange via validated
// __shfl_xor + select (round-4 pattern, 16 words, one latency round).
__global__ __launch_bounds__(256) void attn_fwd(
    const u16* __restrict__ qkv, const u16* __restrict__ vt,
    u16* __restrict__ obuf)
{
    __shared__ __align__(16) u16 lK[2 * 64 * 128];
    __shared__ __align__(16) u16 lV[2 * 128 * 64];
    const int tid  = threadIdx.x;
    const int lane = tid & 63;
    const int w    = tid >> 6;
    const int g    = lane >> 5;
    const int ql   = lane & 31;

    const int bid = blockIdx.x;
    const int qi  = bid >> 5;
    const int bh  = bid & 31;
    const int qtile = (qi < 8) ? (15 - qi) : (qi - 8);  // pair long+short
    const int b = bh >> 4, h = bh & 15;
    const size_t rowbase = (size_t)b * 2048;
    const int qb = qtile * 128;
    const int qw = qb + w * 32;
    const int q  = qw + ql;
    const int nt = 2 * qtile + 2;                  // KV tiles of 64

    const u16* Khead = qkv + rowbase * 6144 + 2048 + h * 128;  // ld 6144
    const u16* Vth   = vt + (size_t)bh * 128 * 2048;           // Vt[d][t]

    // Q as MFMA B-operand frags: qf[ch][j] = Q[q][ch*16 + g*8 + j]
    bf16x8 qf[8];
    {
        const u16* qrow = qkv + (rowbase + q) * 6144 + h * 128;
#pragma unroll
        for (int ch = 0; ch < 8; ++ch)
            qf[ch] = *(const bf16x8*)(qrow + ch * 16 + g * 8);
    }

    f32x16 acc[4];
#pragma unroll
    for (int dt = 0; dt < 4; ++dt)
#pragma unroll
        for (int r = 0; r < 16; ++r) acc[dt][r] = 0.f;

    float m_run = -1e30f, l_run = 0.f;   // l_run: per-lane partial (own half)
    const float C2 = 0.08838834764831845f * 1.44269504088896341f; // scale*log2e

    auto stage = [&](int bb, int t) {
        const int kb = t * 64;
#pragma unroll
        for (int i = 0; i < 4; ++i) {
            const int c = w * 4 + i;
            const int kr = c * 4 + (lane >> 4);
            const u32 kcol = (((u32)((lane & 15) * 16)) ^ ((u32)(kr & 7) << 4)) >> 1;
            gload16(Khead + (size_t)(kb + kr) * 6144 + kcol,
                    lK + bb * 8192 + c * 512);
            const int vr = c * 8 + (lane >> 3);
            const u32 vcol = (((u32)((lane & 7) * 16)) ^ ((u32)(vr & 7) << 4)) >> 1;
            gload16(Vth + (size_t)vr * 2048 + kb + vcol,
                    lV + bb * 8192 + c * 512);
        }
    };

    stage(0, 0);
    __syncthreads();
    int buf = 0;

    for (int t = 0; t < nt; ++t) {
        const int kb = t * 64;
        if (t + 1 < nt) stage(buf ^ 1, t + 1);

        if (kb <= qw + 31) {
            const char* lKb = (const char*)(lK + buf * 8192);
            const char* lVb = (const char*)(lV + buf * 8192);
            const bool f1 = (kb >= qw);            // s1 subtile fully masked
            const bool m0 = (kb == qw);            // s0 diagonal
            const bool m1 = (kb + 32 == qw);       // s1 diagonal

            // ---- QK^T for both 32-kv subtiles ----
            bf16x8 kf0[8], kf1[8];
            const u32 kr0 = (u32)ql, kr1 = (u32)(32 + ql);
            const u32 ks0 = (kr0 & 7) << 4, ks1 = (kr1 & 7) << 4;
#pragma unroll
            for (int ch = 0; ch < 8; ++ch) {
                const u32 byt = (u32)(ch * 32 + g * 16);
                kf0[ch] = *(const bf16x8*)(lKb + kr0 * 256 + (byt ^ ks0));
                kf1[ch] = *(const bf16x8*)(lKb + kr1 * 256 + (byt ^ ks1));
            }
            f32x16 s0_, s1_;
#pragma unroll
            for (int r = 0; r < 16; ++r) { s0_[r] = 0.f; s1_[r] = 0.f; }
            __builtin_amdgcn_s_setprio(1);
#pragma unroll
            for (int ch = 0; ch < 8; ++ch)
                s0_ = __builtin_amdgcn_mfma_f32_32x32x16_bf16(kf0[ch], qf[ch], s0_, 0, 0, 0);
            if (!f1) {
#pragma unroll
                for (int ch = 0; ch < 8; ++ch)
                    s1_ = __builtin_amdgcn_mfma_f32_32x32x16_bf16(kf1[ch], qf[ch], s1_, 0, 0, 0);
            }
            __builtin_amdgcn_s_setprio(0);

            // ---- merged softmax over 64 kv (per-lane: its 32 of 64) ----
            float p[32];
#pragma unroll
            for (int r = 0; r < 16; ++r) p[r] = s0_[r];
            if (m0) {
#pragma unroll
                for (int r = 0; r < 16; ++r) {
                    int crow = (r & 3) + 8 * (r >> 2) + 4 * g;
                    if (crow > ql) p[r] = -1e30f;
                }
            }
            if (f1) {
#pragma unroll
                for (int r = 0; r < 16; ++r) p[16 + r] = -1e30f;
            } else {
#pragma unroll
                for (int r = 0; r < 16; ++r) p[16 + r] = s1_[r];
                if (m1) {
#pragma unroll
                    for (int r = 0; r < 16; ++r) {
                        int crow = (r & 3) + 8 * (r >> 2) + 4 * g;
                        if (crow > ql) p[16 + r] = -1e30f;
                    }
                }
            }
            // per-lane max tree
            float mt[16];
#pragma unroll
            for (int i = 0; i < 16; ++i) mt[i] = fmaxf(p[i], p[i + 16]);
#pragma unroll
            for (int i = 0; i < 8; ++i) mt[i] = fmaxf(mt[i], mt[i + 8]);
#pragma unroll
            for (int i = 0; i < 4; ++i) mt[i] = fmaxf(mt[i], mt[i + 4]);
            float tmax = fmaxf(fmaxf(mt[0], mt[1]), fmaxf(mt[2], mt[3]));

            // T13 defer-max: __all spans both halves, so no per-tile
            // cross-half max needed; joint max only in the rare rescale.
            if (!__all(tmax <= m_run + 8.0f)) {
                float jmax  = fmaxf(tmax, __shfl_xor(tmax, 32));
                float mnew  = fmaxf(m_run, jmax);
                float alpha = exp2f((m_run - mnew) * C2);
#pragma unroll
                for (int dt = 0; dt < 4; ++dt) acc[dt] = acc[dt] * alpha;
                l_run *= alpha;
                m_run = mnew;
            }
#pragma unroll
            for (int r = 0; r < 32; ++r)
                p[r] = exp2f((p[r] - m_run) * C2);
            // per-lane sum tree; keep l_run partial (merge after loop)
            float st[16];
#pragma unroll
            for (int i = 0; i < 16; ++i) st[i] = p[i] + p[i + 16];
#pragma unroll
            for (int i = 0; i < 8; ++i) st[i] += st[i + 8];
#pragma unroll
            for (int i = 0; i < 4; ++i) st[i] += st[i + 4];
            l_run += (st[0] + st[1]) + (st[2] + st[3]);

            // ---- P^T pack + exchange (validated shfl_xor+select) ----
            u32 wv[16], sw[16];
#pragma unroll
            for (int j = 0; j < 16; ++j) wv[j] = pack_bf2(p[2 * j], p[2 * j + 1]);
#pragma unroll
            for (int j = 0; j < 16; ++j) sw[j] = __shfl_xor(wv[j], 32);
            Frag4 pf0, pf1, pf2, pf3;
#pragma unroll
            for (int u = 0; u < 4; ++u) {
                const bool own = (g == (u >> 1));
                const int i0 = 2 * g + (u & 1);
                pf0.u[u] = own ? wv[i0]      : sw[i0];
                pf1.u[u] = own ? wv[4 + i0]  : sw[4 + i0];
                pf2.u[u] = own ? wv[8 + i0]  : sw[8 + i0];
                pf3.u[u] = own ? wv[12 + i0] : sw[12 + i0];
            }

            // ---- PV: O^T += V^T * P^T ----
            __builtin_amdgcn_s_setprio(1);
#pragma unroll
            for (int dt = 0; dt < 4; ++dt) {
                const u32 vrow = (u32)(dt * 32 + ql);
                const u32 vsw = (vrow & 7) << 4;
                bf16x8 v00 = *(const bf16x8*)(lVb + vrow * 128 + (((u32)(g * 16)) ^ vsw));
                bf16x8 v01 = *(const bf16x8*)(lVb + vrow * 128 + (((u32)(32 + g * 16)) ^ vsw));
                acc[dt] = __builtin_amdgcn_mfma_f32_32x32x16_bf16(v00, pf0.v, acc[dt], 0, 0, 0);
                acc[dt] = __builtin_amdgcn_mfma_f32_32x32x16_bf16(v01, pf1.v, acc[dt], 0, 0, 0);
                if (!f1) {
                    bf16x8 v10 = *(const bf16x8*)(lVb + vrow * 128 + (((u32)(64 + g * 16)) ^ vsw));
                    bf16x8 v11 = *(const bf16x8*)(lVb + vrow * 128 + (((u32)(96 + g * 16)) ^ vsw));
                    acc[dt] = __builtin_amdgcn_mfma_f32_32x32x16_bf16(v10, pf2.v, acc[dt], 0, 0, 0);
                    acc[dt] = __builtin_amdgcn_mfma_f32_32x32x16_bf16(v11, pf3.v, acc[dt], 0, 0, 0);
                }
            }
            __builtin_amdgcn_s_setprio(0);
        }
        __syncthreads();   // stage(buf^1) landed; all reads of buf done
        buf ^= 1;
    }

    l_run += __shfl_xor(l_run, 32);     // merge the two half partials
    const float inv_l = 1.0f / l_run;
    u16* orow = obuf + (rowbase + q) * 2048 + h * 128;
#pragma unroll
    for (int dt = 0; dt < 4; ++dt) {
#pragma unroll
        for (int rr = 0; rr < 4; ++rr) {
            int d0 = dt * 32 + rr * 8 + g * 4;   // d' = (r&3)+8*(r>>2)+4g+32dt
            int r0 = rr * 4;
            u32 w0 = pack_bf2(acc[dt][r0] * inv_l,     acc[dt][r0 + 1] * inv_l);
            u32 w1 = pack_bf2(acc[dt][r0 + 2] * inv_l, acc[dt][r0 + 3] * inv_l);
            *(u32*)(orow + d0)     = w0;
            *(u32*)(orow + d0 + 2) = w1;
        }
    }
}

extern "C" void kernel_launch(void* const* d_in, const int* in_sizes, int n_in,
                              void* d_out, int out_size, void* d_ws, size_t ws_size,
                              hipStream_t stream) {
    (void)in_sizes; (void)n_in; (void)out_size; (void)ws_size;
    const float* x    = (const float*)d_in[0];
    const float* Wqkv = (const float*)d_in[1];
    const float* bqkv = (const float*)d_in[2];
    const float* Wout = (const float*)d_in[3];
    const float* bout = (const float*)d_in[4];

    char* ws = (char*)d_ws;
    u16* xb  = (u16*)ws;                        // [4096,2048] bf16, 16 MB
    u16* wqb = (u16*)(ws + (size_t)16777216);   // [6144,2048] bf16, 24 MB
    u16* qkv = (u16*)(ws + (size_t)41943040);   // [4096,6144] bf16, 48 MB
    u16* ob  = xb;   // attention out reuses xb (x dead after GEMM1)
    u16* vtb = wqb;  // V^T [32,128,2048] bf16 16 MB reuses wqb
    u16* wob = wqb;  // W_out bf16 reuses wqb again (vtb dead after attn)

    cvt_f32_bf16<<<2048, 256, 0, stream>>>(x, xb, 8388608L / 8);
    cvt_f32_bf16<<<2048, 256, 0, stream>>>(Wqkv, wqb, 12582912L / 8);
    gemm_nt<1><<<1536, 256, 0, stream>>>(xb, wqb, bqkv, qkv, 2048, 6144, 5);
    transpose_v<<<2048, 256, 0, stream>>>(qkv, vtb);
    attn_fwd<<<512, 256, 0, stream>>>(qkv, vtb, ob);
    cvt_f32_bf16<<<2048, 256, 0, stream>>>(Wout, wob, 4194304L / 8);
    gemm_nt<0><<<512, 256, 0, stream>>>(ob, wob, bout, d_out, 2048, 2048, 5);
}

// Round 7
// 349.758 us; speedup vs baseline: 1.1068x; 1.1068x over previous
//
#include <hip/hip_runtime.h>
#include <stdint.h>

typedef short bf16x8 __attribute__((ext_vector_type(8)));
typedef float f32x4 __attribute__((ext_vector_type(4)));
typedef float f32x16 __attribute__((ext_vector_type(16)));
typedef unsigned short u16;
typedef unsigned int u32;

__device__ __forceinline__ u16 f2bf(float f) {
    u32 x = __float_as_uint(f);
    x += 0x7fffu + ((x >> 16) & 1u);
    return (u16)(x >> 16);
}
__device__ __forceinline__ u32 pack_bf2(float a, float b) {
    return (u32)f2bf(a) | ((u32)f2bf(b) << 16);
}

union Frag4 { u32 u[4]; bf16x8 v; };

// async global->LDS, 16B per lane; LDS dest is wave-uniform base + lane*16
__device__ __forceinline__ void gload16(const u16* g, u16* l) {
    __builtin_amdgcn_global_load_lds(
        (__attribute__((address_space(1))) void*)g,
        (__attribute__((address_space(3))) void*)l,
        16, 0, 0);
}

// ---------------- f32 -> bf16 cast, 8 elems/thread (G13: vectorized) --------
__global__ void cvt_f32_bf16(const float* __restrict__ in, u16* __restrict__ out, long n8) {
    long stride = (long)gridDim.x * blockDim.x;
    for (long i = (long)blockIdx.x * blockDim.x + threadIdx.x; i < n8; i += stride) {
        const float4* p = (const float4*)(in + i * 8);
        float4 a = p[0], b = p[1];
        uint4 o;
        o.x = pack_bf2(a.x, a.y);
        o.y = pack_bf2(a.z, a.w);
        o.z = pack_bf2(b.x, b.y);
        o.w = pack_bf2(b.z, b.w);
        ((uint4*)out)[i] = o;
    }
}

// ---------------- bf16 NT GEMM: out = A * B^T + bias ------------------------
// 128x128 tile, BK=64, 4 waves (2x2 of 64x64), dbuf LDS (64KB),
// T4 counted-vmcnt pipeline: stage(t+2) after compute(t), raw s_barrier +
// s_waitcnt vmcnt(8) (never 0 mid-loop) so 8 loads stay in flight across
// the next K-tile's compute. Swizzled staging source + ds_read (rule #21).
template<int OBF>
__global__ __launch_bounds__(256, 2) void gemm_nt(
    const u16* __restrict__ A, const u16* __restrict__ B,
    const float* __restrict__ bias, void* __restrict__ out,
    int K, int ldo, int gxsh)
{
    __shared__ __align__(16) u16 lA[2 * 128 * 64];
    __shared__ __align__(16) u16 lB[2 * 128 * 64];
    const int tid  = threadIdx.x;
    const int lane = tid & 63;
    const int w    = tid >> 6;
    const int wm = (w >> 1) * 64, wn = (w & 1) * 64;

    // XCD-aware bijective swizzle (nwg % 8 == 0 for both call sites)
    const int nwg = gridDim.x;
    const int bid = blockIdx.x;
    const int swz = (bid & 7) * (nwg >> 3) + (bid >> 3);
    const int bm = (swz & ((1 << gxsh) - 1)) * 128;
    const int bn = (swz >> gxsh) * 128;

    const int lr = lane >> 3;                       // row within chunk
    const u32 sb = (u32)((lane & 7) * 16);          // stored byte-in-row
    const int NT = K >> 6;

    auto stage = [&](int bb, int k0) {
#pragma unroll
        for (int i = 0; i < 4; ++i) {
            const int c = w * 4 + i;               // wave-uniform chunk id
            const int row = c * 8 + lr;
            const u32 col = (sb ^ ((u32)(row & 7) << 4)) >> 1;   // elems
            gload16(A + (size_t)(bm + row) * K + k0 + col, lA + bb * 8192 + c * 512);
            gload16(B + (size_t)(bn + row) * K + k0 + col, lB + bb * 8192 + c * 512);
        }
    };

    f32x4 acc[4][4];
#pragma unroll
    for (int i = 0; i < 4; ++i)
#pragma unroll
        for (int j = 0; j < 4; ++j)
#pragma unroll
            for (int r = 0; r < 4; ++r) acc[i][j][r] = 0.f;

    // prologue: two K-tiles in flight; drain only the first
    stage(0, 0);
    stage(1, 64);
    asm volatile("s_waitcnt vmcnt(8)" ::: "memory");
    __builtin_amdgcn_sched_barrier(0);
    __builtin_amdgcn_s_barrier();
    __builtin_amdgcn_sched_barrier(0);

    for (int t = 0; t < NT; ++t) {
        const int cur = t & 1;
        const char* pA = (const char*)(lA + cur * 8192);
        const char* pB = (const char*)(lB + cur * 8192);
#pragma unroll
        for (int kk = 0; kk < 2; ++kk) {
            bf16x8 af[4], bfr[4];
#pragma unroll
            for (int f = 0; f < 4; ++f) {
                const int m = wm + f * 16 + (lane & 15);
                const u32 byt = (u32)(kk * 64 + (lane >> 4) * 16) ^ ((u32)(m & 7) << 4);
                af[f]  = *(const bf16x8*)(pA + m * 128 + byt);
                const int n = wn + f * 16 + (lane & 15);
                const u32 bytb = (u32)(kk * 64 + (lane >> 4) * 16) ^ ((u32)(n & 7) << 4);
                bfr[f] = *(const bf16x8*)(pB + n * 128 + bytb);
            }
            __builtin_amdgcn_s_setprio(1);
#pragma unroll
            for (int i = 0; i < 4; ++i)
#pragma unroll
                for (int j = 0; j < 4; ++j)
                    acc[i][j] = __builtin_amdgcn_mfma_f32_16x16x32_bf16(af[i], bfr[j], acc[i][j], 0, 0, 0);
            __builtin_amdgcn_s_setprio(0);
        }
        // all waves done reading buf cur
        __builtin_amdgcn_sched_barrier(0);
        __builtin_amdgcn_s_barrier();
        __builtin_amdgcn_sched_barrier(0);
        // prefetch K-tile t+2 into buf cur; drain t+1's loads (oldest 8),
        // leaving t+2's 8 in flight across the next K-tile's compute
        if (t + 2 < NT) {
            stage(cur, (t + 2) * 64);
            asm volatile("s_waitcnt vmcnt(8)" ::: "memory");
        } else {
            asm volatile("s_waitcnt vmcnt(0)" ::: "memory");
        }
        __builtin_amdgcn_sched_barrier(0);
        __builtin_amdgcn_s_barrier();
        __builtin_amdgcn_sched_barrier(0);
    }

    // epilogue: C/D layout col=lane&15, row=(lane>>4)*4+reg (m89-verified)
#pragma unroll
    for (int i = 0; i < 4; ++i) {
        int m0 = bm + wm + i * 16 + ((lane >> 4) << 2);
#pragma unroll
        for (int j = 0; j < 4; ++j) {
            int n = bn + wn + j * 16 + (lane & 15);
            float bv = bias[n];
#pragma unroll
            for (int r = 0; r < 4; ++r) {
                float v = acc[i][j][r] + bv;
                if constexpr (OBF != 0)
                    ((u16*)out)[(size_t)(m0 + r) * ldo + n] = f2bf(v);
                else
                    ((float*)out)[(size_t)(m0 + r) * ldo + n] = v;
            }
        }
    }
}

// ---------------- V transpose: vt[b,h,d,t] <- qkv[b*2048+t][4096+h*128+d] ---
__global__ __launch_bounds__(256) void transpose_v(
    const u16* __restrict__ qkv, u16* __restrict__ vt)
{
    __shared__ u16 lt[64 * 64];   // rows of 128B, slot XOR-swizzled
    const int tid = threadIdx.x;
    const int bid = blockIdx.x;
    const int tt    = bid & 31;
    const int dtile = (bid >> 5) & 1;
    const int h     = (bid >> 6) & 15;
    const int b     = bid >> 10;
    const u16* src = qkv + ((size_t)b * 2048 + tt * 64) * 6144 + 4096 + h * 128 + dtile * 64;

    const int r = tid >> 2, ce = (tid & 3) * 16;   // row t, elem col in tile
    uint4 a0 = *(const uint4*)(src + (size_t)r * 6144 + ce);
    uint4 a1 = *(const uint4*)(src + (size_t)r * 6144 + ce + 8);
    const u32 swz = (u32)((r & 7) << 4);
    *(uint4*)((char*)lt + r * 128 + (((u32)(ce * 2)) ^ swz)) = a0;
    *(uint4*)((char*)lt + r * 128 + (((u32)(ce * 2 + 16)) ^ swz)) = a1;
    __syncthreads();

    const int d = tid >> 2;
    u16* dst = vt + ((size_t)(b * 16 + h) * 128 + dtile * 64 + d) * 2048 + tt * 64;
#pragma unroll
    for (int it = 0; it < 2; ++it) {
        const int t0 = (tid & 3) * 8 + it * 32;
        union { u16 hh[8]; uint4 q4; } u;
#pragma unroll
        for (int uu = 0; uu < 8; ++uu) {
            int trow = t0 + uu;
            u32 byt = (u32)(trow * 128) + (((u32)(d * 2)) ^ ((u32)((trow & 7) << 4)));
            u.hh[uu] = *(const u16*)((const char*)lt + byt);
        }
        *(uint4*)(dst + t0) = u.q4;
    }
}

// ---------------- causal flash attention (round-4 validated version) --------
// Block = (b, h, 128 q rows); 4 waves x 32 q rows. KVBLK=64 double-buffered.
// Per-32-kv subtile softmax (compiler interleaves s0 softmax with s1 MFMA).
__global__ __launch_bounds__(256) void attn_fwd(
    const u16* __restrict__ qkv, const u16* __restrict__ vt,
    u16* __restrict__ obuf)
{
    __shared__ __align__(16) u16 lK[2 * 64 * 128];
    __shared__ __align__(16) u16 lV[2 * 128 * 64];
    const int tid  = threadIdx.x;
    const int lane = tid & 63;
    const int w    = tid >> 6;
    const int g    = lane >> 5;
    const int ql   = lane & 31;

    const int bid = blockIdx.x;
    const int qi  = bid >> 5;
    const int bh  = bid & 31;
    const int qtile = (qi < 8) ? (15 - qi) : (qi - 8);  // pair long+short
    const int b = bh >> 4, h = bh & 15;
    const size_t rowbase = (size_t)b * 2048;
    const int qb = qtile * 128;
    const int qw = qb + w * 32;
    const int q  = qw + ql;
    const int nt = 2 * qtile + 2;                  // KV tiles of 64

    const u16* Khead = qkv + rowbase * 6144 + 2048 + h * 128;  // ld 6144
    const u16* Vth   = vt + (size_t)bh * 128 * 2048;           // Vt[d][t]

    // Q as MFMA B-operand frags: qf[ch][j] = Q[q][ch*16 + g*8 + j]
    bf16x8 qf[8];
    {
        const u16* qrow = qkv + (rowbase + q) * 6144 + h * 128;
#pragma unroll
        for (int ch = 0; ch < 8; ++ch)
            qf[ch] = *(const bf16x8*)(qrow + ch * 16 + g * 8);
    }

    f32x16 acc[4];
#pragma unroll
    for (int dt = 0; dt < 4; ++dt)
#pragma unroll
        for (int r = 0; r < 16; ++r) acc[dt][r] = 0.f;

    float m_run = -1e30f, l_run = 0.f;
    const float C2 = 0.08838834764831845f * 1.44269504088896341f; // scale*log2e

    auto stage = [&](int bb, int t) {
        const int kb = t * 64;
#pragma unroll
        for (int i = 0; i < 4; ++i) {
            const int c = w * 4 + i;
            const int kr = c * 4 + (lane >> 4);
            const u32 kcol = (((u32)((lane & 15) * 16)) ^ ((u32)(kr & 7) << 4)) >> 1;
            gload16(Khead + (size_t)(kb + kr) * 6144 + kcol,
                    lK + bb * 8192 + c * 512);
            const int vr = c * 8 + (lane >> 3);
            const u32 vcol = (((u32)((lane & 7) * 16)) ^ ((u32)(vr & 7) << 4)) >> 1;
            gload16(Vth + (size_t)vr * 2048 + kb + vcol,
                    lV + bb * 8192 + c * 512);
        }
    };

    stage(0, 0);
    __syncthreads();
    int buf = 0;

    for (int t = 0; t < nt; ++t) {
        const int kb = t * 64;
        if (t + 1 < nt) stage(buf ^ 1, t + 1);

        if (kb <= qw + 31) {
            const char* lKb = (const char*)(lK + buf * 8192);
            const char* lVb = (const char*)(lV + buf * 8192);
#pragma unroll
            for (int s = 0; s < 2; ++s) {
                const int kb2 = kb + s * 32;
                if (kb2 > qw + 31) break;          // wave-uniform
                const bool diag = (kb2 == qw);

                // K frags from LDS (swizzled)
                bf16x8 kf[8];
                const u32 krow = (u32)(s * 32 + ql);
                const u32 ksw = (krow & 7) << 4;
#pragma unroll
                for (int ch = 0; ch < 8; ++ch)
                    kf[ch] = *(const bf16x8*)(lKb + krow * 256 + (((u32)(ch * 32 + g * 16)) ^ ksw));

                f32x16 s_;
#pragma unroll
                for (int r = 0; r < 16; ++r) s_[r] = 0.f;
                __builtin_amdgcn_s_setprio(1);
#pragma unroll
                for (int ch = 0; ch < 8; ++ch)
                    s_ = __builtin_amdgcn_mfma_f32_32x32x16_bf16(kf[ch], qf[ch], s_, 0, 0, 0);
                __builtin_amdgcn_s_setprio(0);

                // lane holds S^T[k'][q], k'(r) = (r&3)+8*(r>>2)+4*g
                float p[16];
                float tmax = -1e30f;
#pragma unroll
                for (int r = 0; r < 16; ++r) {
                    int crow = (r & 3) + 8 * (r >> 2) + 4 * g;
                    float v = s_[r];
                    if (diag && (crow > ql)) v = -1e30f;   // causal mask
                    p[r] = v;
                    tmax = fmaxf(tmax, v);
                }
                tmax = fmaxf(tmax, __shfl_xor(tmax, 32));
                // T13 defer-max: skip O/l rescale while max grows < 8
                if (!__all(tmax <= m_run + 8.0f)) {
                    float mnew  = fmaxf(m_run, tmax);
                    float alpha = exp2f((m_run - mnew) * C2);
#pragma unroll
                    for (int dt = 0; dt < 4; ++dt) acc[dt] = acc[dt] * alpha;
                    l_run *= alpha;
                    m_run = mnew;
                }
                float ssum = 0.f;
#pragma unroll
                for (int r = 0; r < 16; ++r) {
                    float e = exp2f((p[r] - m_run) * C2);
                    p[r] = e;
                    ssum += e;
                }
                ssum += __shfl_xor(ssum, 32);
                l_run += ssum;

                // P^T -> MFMA B-operand frags via one cross-half exchange
                u32 wb[8], sw[8];
#pragma unroll
                for (int j = 0; j < 8; ++j) wb[j] = pack_bf2(p[2 * j], p[2 * j + 1]);
#pragma unroll
                for (int j = 0; j < 8; ++j) sw[j] = __shfl_xor(wb[j], 32);
                Frag4 pf0, pf1;
#pragma unroll
                for (int u = 0; u < 4; ++u) {
                    const bool own = (g == (u >> 1));
                    pf0.u[u] = own ? wb[2 * g + (u & 1)]     : sw[2 * g + (u & 1)];
                    pf1.u[u] = own ? wb[4 + 2 * g + (u & 1)] : sw[4 + 2 * g + (u & 1)];
                }

                // O^T += V^T * P^T ; V^T frags from LDS (swizzled)
                __builtin_amdgcn_s_setprio(1);
#pragma unroll
                for (int dt = 0; dt < 4; ++dt) {
                    const u32 vrow = (u32)(dt * 32 + ql);
                    const u32 vsw = (vrow & 7) << 4;
                    bf16x8 v0 = *(const bf16x8*)(lVb + vrow * 128 + (((u32)(s * 64 + g * 16)) ^ vsw));
                    bf16x8 v1 = *(const bf16x8*)(lVb + vrow * 128 + (((u32)(s * 64 + 32 + g * 16)) ^ vsw));
                    acc[dt] = __builtin_amdgcn_mfma_f32_32x32x16_bf16(v0, pf0.v, acc[dt], 0, 0, 0);
                    acc[dt] = __builtin_amdgcn_mfma_f32_32x32x16_bf16(v1, pf1.v, acc[dt], 0, 0, 0);
                }
                __builtin_amdgcn_s_setprio(0);
            }
        }
        __syncthreads();   // stage(buf^1) landed; all reads of buf done
        buf ^= 1;
    }

    const float inv_l = 1.0f / l_run;
    u16* orow = obuf + (rowbase + q) * 2048 + h * 128;
#pragma unroll
    for (int dt = 0; dt < 4; ++dt) {
#pragma unroll
        for (int rr = 0; rr < 4; ++rr) {
            int d0 = dt * 32 + rr * 8 + g * 4;   // d' = (r&3)+8*(r>>2)+4g+32dt
            int r0 = rr * 4;
            u32 w0 = pack_bf2(acc[dt][r0] * inv_l,     acc[dt][r0 + 1] * inv_l);
            u32 w1 = pack_bf2(acc[dt][r0 + 2] * inv_l, acc[dt][r0 + 3] * inv_l);
            *(u32*)(orow + d0)     = w0;
            *(u32*)(orow + d0 + 2) = w1;
        }
    }
}

extern "C" void kernel_launch(void* const* d_in, const int* in_sizes, int n_in,
                              void* d_out, int out_size, void* d_ws, size_t ws_size,
                              hipStream_t stream) {
    (void)in_sizes; (void)n_in; (void)out_size; (void)ws_size;
    const float* x    = (const float*)d_in[0];
    const float* Wqkv = (const float*)d_in[1];
    const float* bqkv = (const float*)d_in[2];
    const float* Wout = (const float*)d_in[3];
    const float* bout = (const float*)d_in[4];

    char* ws = (char*)d_ws;
    u16* xb  = (u16*)ws;                        // [4096,2048] bf16, 16 MB
    u16* wqb = (u16*)(ws + (size_t)16777216);   // [6144,2048] bf16, 24 MB
    u16* qkv = (u16*)(ws + (size_t)41943040);   // [4096,6144] bf16, 48 MB
    u16* ob  = xb;   // attention out reuses xb (x dead after GEMM1)
    u16* vtb = wqb;  // V^T [32,128,2048] bf16 16 MB reuses wqb
    u16* wob = wqb;  // W_out bf16 reuses wqb again (vtb dead after attn)

    cvt_f32_bf16<<<2048, 256, 0, stream>>>(x, xb, 8388608L / 8);
    cvt_f32_bf16<<<2048, 256, 0, stream>>>(Wqkv, wqb, 12582912L / 8);
    gemm_nt<1><<<1536, 256, 0, stream>>>(xb, wqb, bqkv, qkv, 2048, 6144, 5);
    transpose_v<<<2048, 256, 0, stream>>>(qkv, vtb);
    attn_fwd<<<512, 256, 0, stream>>>(qkv, vtb, ob);
    cvt_f32_bf16<<<2048, 256, 0, stream>>>(Wout, wob, 4194304L / 8);
    gemm_nt<0><<<512, 256, 0, stream>>>(ob, wob, bout, d_out, 2048, 2048, 5);
}

// Round 8
// 347.730 us; speedup vs baseline: 1.1132x; 1.0058x over previous
//
#include <hip/hip_runtime.h>
#include <stdint.h>

typedef short bf16x8 __attribute__((ext_vector_type(8)));
typedef float f32x4 __attribute__((ext_vector_type(4)));
typedef float f32x16 __attribute__((ext_vector_type(16)));
typedef unsigned short u16;
typedef unsigned int u32;

__device__ __forceinline__ u16 f2bf(float f) {
    u32 x = __float_as_uint(f);
    x += 0x7fffu + ((x >> 16) & 1u);
    return (u16)(x >> 16);
}
__device__ __forceinline__ u32 pack_bf2(float a, float b) {
    return (u32)f2bf(a) | ((u32)f2bf(b) << 16);
}

union Frag4 { u32 u[4]; bf16x8 v; };

// async global->LDS, 16B per lane; LDS dest is wave-uniform base + lane*16
__device__ __forceinline__ void gload16(const u16* g, u16* l) {
    __builtin_amdgcn_global_load_lds(
        (__attribute__((address_space(1))) void*)g,
        (__attribute__((address_space(3))) void*)l,
        16, 0, 0);
}

// ---------------- f32 -> bf16 cast, 8 elems/thread (G13: vectorized) --------
__global__ void cvt_f32_bf16(const float* __restrict__ in, u16* __restrict__ out, long n8) {
    long stride = (long)gridDim.x * blockDim.x;
    for (long i = (long)blockIdx.x * blockDim.x + threadIdx.x; i < n8; i += stride) {
        const float4* p = (const float4*)(in + i * 8);
        float4 a = p[0], b = p[1];
        uint4 o;
        o.x = pack_bf2(a.x, a.y);
        o.y = pack_bf2(a.z, a.w);
        o.z = pack_bf2(b.x, b.y);
        o.w = pack_bf2(b.z, b.w);
        ((uint4*)out)[i] = o;
    }
}

// ---------------- bf16 NT GEMM: out = A * B^T + bias ------------------------
// 128x128 tile, BK=64, 4 waves, dbuf LDS, T4 counted-vmcnt pipeline
// (stage t+2 after compute t, vmcnt(8) mid-loop). Validated round 7.
template<int OBF>
__global__ __launch_bounds__(256, 2) void gemm_nt(
    const u16* __restrict__ A, const u16* __restrict__ B,
    const float* __restrict__ bias, void* __restrict__ out,
    int K, int ldo, int gxsh)
{
    __shared__ __align__(16) u16 lA[2 * 128 * 64];
    __shared__ __align__(16) u16 lB[2 * 128 * 64];
    const int tid  = threadIdx.x;
    const int lane = tid & 63;
    const int w    = tid >> 6;
    const int wm = (w >> 1) * 64, wn = (w & 1) * 64;

    const int nwg = gridDim.x;
    const int bid = blockIdx.x;
    const int swz = (bid & 7) * (nwg >> 3) + (bid >> 3);
    const int bm = (swz & ((1 << gxsh) - 1)) * 128;
    const int bn = (swz >> gxsh) * 128;

    const int lr = lane >> 3;
    const u32 sb = (u32)((lane & 7) * 16);
    const int NT = K >> 6;

    auto stage = [&](int bb, int k0) {
#pragma unroll
        for (int i = 0; i < 4; ++i) {
            const int c = w * 4 + i;
            const int row = c * 8 + lr;
            const u32 col = (sb ^ ((u32)(row & 7) << 4)) >> 1;
            gload16(A + (size_t)(bm + row) * K + k0 + col, lA + bb * 8192 + c * 512);
            gload16(B + (size_t)(bn + row) * K + k0 + col, lB + bb * 8192 + c * 512);
        }
    };

    f32x4 acc[4][4];
#pragma unroll
    for (int i = 0; i < 4; ++i)
#pragma unroll
        for (int j = 0; j < 4; ++j)
#pragma unroll
            for (int r = 0; r < 4; ++r) acc[i][j][r] = 0.f;

    stage(0, 0);
    stage(1, 64);
    asm volatile("s_waitcnt vmcnt(8)" ::: "memory");
    __builtin_amdgcn_sched_barrier(0);
    __builtin_amdgcn_s_barrier();
    __builtin_amdgcn_sched_barrier(0);

    for (int t = 0; t < NT; ++t) {
        const int cur = t & 1;
        const char* pA = (const char*)(lA + cur * 8192);
        const char* pB = (const char*)(lB + cur * 8192);
#pragma unroll
        for (int kk = 0; kk < 2; ++kk) {
            bf16x8 af[4], bfr[4];
#pragma unroll
            for (int f = 0; f < 4; ++f) {
                const int m = wm + f * 16 + (lane & 15);
                const u32 byt = (u32)(kk * 64 + (lane >> 4) * 16) ^ ((u32)(m & 7) << 4);
                af[f]  = *(const bf16x8*)(pA + m * 128 + byt);
                const int n = wn + f * 16 + (lane & 15);
                const u32 bytb = (u32)(kk * 64 + (lane >> 4) * 16) ^ ((u32)(n & 7) << 4);
                bfr[f] = *(const bf16x8*)(pB + n * 128 + bytb);
            }
            __builtin_amdgcn_s_setprio(1);
#pragma unroll
            for (int i = 0; i < 4; ++i)
#pragma unroll
                for (int j = 0; j < 4; ++j)
                    acc[i][j] = __builtin_amdgcn_mfma_f32_16x16x32_bf16(af[i], bfr[j], acc[i][j], 0, 0, 0);
            __builtin_amdgcn_s_setprio(0);
        }
        __builtin_amdgcn_sched_barrier(0);
        __builtin_amdgcn_s_barrier();
        __builtin_amdgcn_sched_barrier(0);
        if (t + 2 < NT) {
            stage(cur, (t + 2) * 64);
            asm volatile("s_waitcnt vmcnt(8)" ::: "memory");
        } else {
            asm volatile("s_waitcnt vmcnt(0)" ::: "memory");
        }
        __builtin_amdgcn_sched_barrier(0);
        __builtin_amdgcn_s_barrier();
        __builtin_amdgcn_sched_barrier(0);
    }

#pragma unroll
    for (int i = 0; i < 4; ++i) {
        int m0 = bm + wm + i * 16 + ((lane >> 4) << 2);
#pragma unroll
        for (int j = 0; j < 4; ++j) {
            int n = bn + wn + j * 16 + (lane & 15);
            float bv = bias[n];
#pragma unroll
            for (int r = 0; r < 4; ++r) {
                float v = acc[i][j][r] + bv;
                if constexpr (OBF != 0)
                    ((u16*)out)[(size_t)(m0 + r) * ldo + n] = f2bf(v);
                else
                    ((float*)out)[(size_t)(m0 + r) * ldo + n] = v;
            }
        }
    }
}

// ---------------- V transpose: vt[b,h,d,t] <- qkv[b*2048+t][4096+h*128+d] ---
__global__ __launch_bounds__(256) void transpose_v(
    const u16* __restrict__ qkv, u16* __restrict__ vt)
{
    __shared__ u16 lt[64 * 64];
    const int tid = threadIdx.x;
    const int bid = blockIdx.x;
    const int tt    = bid & 31;
    const int dtile = (bid >> 5) & 1;
    const int h     = (bid >> 6) & 15;
    const int b     = bid >> 10;
    const u16* src = qkv + ((size_t)b * 2048 + tt * 64) * 6144 + 4096 + h * 128 + dtile * 64;

    const int r = tid >> 2, ce = (tid & 3) * 16;
    uint4 a0 = *(const uint4*)(src + (size_t)r * 6144 + ce);
    uint4 a1 = *(const uint4*)(src + (size_t)r * 6144 + ce + 8);
    const u32 swz = (u32)((r & 7) << 4);
    *(uint4*)((char*)lt + r * 128 + (((u32)(ce * 2)) ^ swz)) = a0;
    *(uint4*)((char*)lt + r * 128 + (((u32)(ce * 2 + 16)) ^ swz)) = a1;
    __syncthreads();

    const int d = tid >> 2;
    u16* dst = vt + ((size_t)(b * 16 + h) * 128 + dtile * 64 + d) * 2048 + tt * 64;
#pragma unroll
    for (int it = 0; it < 2; ++it) {
        const int t0 = (tid & 3) * 8 + it * 32;
        union { u16 hh[8]; uint4 q4; } u;
#pragma unroll
        for (int uu = 0; uu < 8; ++uu) {
            int trow = t0 + uu;
            u32 byt = (u32)(trow * 128) + (((u32)(d * 2)) ^ ((u32)((trow & 7) << 4)));
            u.hh[uu] = *(const u16*)((const char*)lt + byt);
        }
        *(uint4*)(dst + t0) = u.q4;
    }
}

// ---------------- causal flash attention (KV-split, round-4 inner loop) -----
// 768 blocks, longest-first: qt>=8 split into 2 KV chunks (chunk0 unmasked,
// chunk1 owns diagonal) writing f32 partials (O^T,m,l); qt<8 unsplit writes
// ob directly. Partial O lives in d_out (free scratch before gemm2).
__constant__ unsigned char QT_TAB[24] = {15,15,7,14,14,13,13,6,12,12,11,11,5,10,10,9,9,4,8,8,3,2,1,0};
__constant__ unsigned char CK_TAB[24] = {0,1,2,0,1,0,1,2,0,1,0,1,2,0,1,0,1,2,0,1,2,2,2,2};

__global__ __launch_bounds__(256) void attn_fwd(
    const u16* __restrict__ qkv, const u16* __restrict__ vt,
    u16* __restrict__ obuf, float* __restrict__ pout, float* __restrict__ pml)
{
    __shared__ __align__(16) u16 lK[2 * 64 * 128];
    __shared__ __align__(16) u16 lV[2 * 128 * 64];
    const int tid  = threadIdx.x;
    const int lane = tid & 63;
    const int w    = tid >> 6;
    const int g    = lane >> 5;
    const int ql   = lane & 31;

    const int bid  = blockIdx.x;
    const int item = bid >> 5;
    const int bh   = bid & 31;
    const int qt   = QT_TAB[item];
    const int ck   = CK_TAB[item];
    const int b = bh >> 4, h = bh & 15;
    const size_t rowbase = (size_t)b * 2048;
    const int qb = qt * 128;
    const int qw = qb + w * 32;
    const int q  = qw + ql;
    const int t_lo = (ck == 1) ? (qt + 1) : 0;
    const int t_hi = (ck == 0) ? (qt + 1) : (2 * qt + 2);

    const u16* Khead = qkv + rowbase * 6144 + 2048 + h * 128;  // ld 6144
    const u16* Vth   = vt + (size_t)bh * 128 * 2048;           // Vt[d][t]

    bf16x8 qf[8];
    {
        const u16* qrow = qkv + (rowbase + q) * 6144 + h * 128;
#pragma unroll
        for (int ch = 0; ch < 8; ++ch)
            qf[ch] = *(const bf16x8*)(qrow + ch * 16 + g * 8);
    }

    f32x16 acc[4];
#pragma unroll
    for (int dt = 0; dt < 4; ++dt)
#pragma unroll
        for (int r = 0; r < 16; ++r) acc[dt][r] = 0.f;

    float m_run = -1e30f, l_run = 0.f;
    const float C2 = 0.08838834764831845f * 1.44269504088896341f; // scale*log2e

    auto stage = [&](int bb, int t) {
        const int kb = t * 64;
#pragma unroll
        for (int i = 0; i < 4; ++i) {
            const int c = w * 4 + i;
            const int kr = c * 4 + (lane >> 4);
            const u32 kcol = (((u32)((lane & 15) * 16)) ^ ((u32)(kr & 7) << 4)) >> 1;
            gload16(Khead + (size_t)(kb + kr) * 6144 + kcol,
                    lK + bb * 8192 + c * 512);
            const int vr = c * 8 + (lane >> 3);
            const u32 vcol = (((u32)((lane & 7) * 16)) ^ ((u32)(vr & 7) << 4)) >> 1;
            gload16(Vth + (size_t)vr * 2048 + kb + vcol,
                    lV + bb * 8192 + c * 512);
        }
    };

    stage(0, t_lo);
    __syncthreads();
    int buf = 0;

    for (int t = t_lo; t < t_hi; ++t) {
        const int kb = t * 64;
        if (t + 1 < t_hi) stage(buf ^ 1, t + 1);

        if (kb <= qw + 31) {
            const char* lKb = (const char*)(lK + buf * 8192);
            const char* lVb = (const char*)(lV + buf * 8192);
#pragma unroll
            for (int s = 0; s < 2; ++s) {
                const int kb2 = kb + s * 32;
                if (kb2 > qw + 31) break;          // wave-uniform
                const bool diag = (kb2 == qw);

                bf16x8 kf[8];
                const u32 krow = (u32)(s * 32 + ql);
                const u32 ksw = (krow & 7) << 4;
#pragma unroll
                for (int ch = 0; ch < 8; ++ch)
                    kf[ch] = *(const bf16x8*)(lKb + krow * 256 + (((u32)(ch * 32 + g * 16)) ^ ksw));

                f32x16 s_;
#pragma unroll
                for (int r = 0; r < 16; ++r) s_[r] = 0.f;
                __builtin_amdgcn_s_setprio(1);
#pragma unroll
                for (int ch = 0; ch < 8; ++ch)
                    s_ = __builtin_amdgcn_mfma_f32_32x32x16_bf16(kf[ch], qf[ch], s_, 0, 0, 0);
                __builtin_amdgcn_s_setprio(0);

                float p[16];
                float tmax = -1e30f;
#pragma unroll
                for (int r = 0; r < 16; ++r) {
                    int crow = (r & 3) + 8 * (r >> 2) + 4 * g;
                    float v = s_[r];
                    if (diag && (crow > ql)) v = -1e30f;   // causal mask
                    p[r] = v;
                    tmax = fmaxf(tmax, v);
                }
                tmax = fmaxf(tmax, __shfl_xor(tmax, 32));
                if (!__all(tmax <= m_run + 8.0f)) {
                    float mnew  = fmaxf(m_run, tmax);
                    float alpha = exp2f((m_run - mnew) * C2);
#pragma unroll
                    for (int dt = 0; dt < 4; ++dt) acc[dt] = acc[dt] * alpha;
                    l_run *= alpha;
                    m_run = mnew;
                }
                float ssum = 0.f;
#pragma unroll
                for (int r = 0; r < 16; ++r) {
                    float e = exp2f((p[r] - m_run) * C2);
                    p[r] = e;
                    ssum += e;
                }
                ssum += __shfl_xor(ssum, 32);
                l_run += ssum;

                u32 wb[8], sw[8];
#pragma unroll
                for (int j = 0; j < 8; ++j) wb[j] = pack_bf2(p[2 * j], p[2 * j + 1]);
#pragma unroll
                for (int j = 0; j < 8; ++j) sw[j] = __shfl_xor(wb[j], 32);
                Frag4 pf0, pf1;
#pragma unroll
                for (int u = 0; u < 4; ++u) {
                    const bool own = (g == (u >> 1));
                    pf0.u[u] = own ? wb[2 * g + (u & 1)]     : sw[2 * g + (u & 1)];
                    pf1.u[u] = own ? wb[4 + 2 * g + (u & 1)] : sw[4 + 2 * g + (u & 1)];
                }

                __builtin_amdgcn_s_setprio(1);
#pragma unroll
                for (int dt = 0; dt < 4; ++dt) {
                    const u32 vrow = (u32)(dt * 32 + ql);
                    const u32 vsw = (vrow & 7) << 4;
                    bf16x8 v0 = *(const bf16x8*)(lVb + vrow * 128 + (((u32)(s * 64 + g * 16)) ^ vsw));
                    bf16x8 v1 = *(const bf16x8*)(lVb + vrow * 128 + (((u32)(s * 64 + 32 + g * 16)) ^ vsw));
                    acc[dt] = __builtin_amdgcn_mfma_f32_32x32x16_bf16(v0, pf0.v, acc[dt], 0, 0, 0);
                    acc[dt] = __builtin_amdgcn_mfma_f32_32x32x16_bf16(v1, pf1.v, acc[dt], 0, 0, 0);
                }
                __builtin_amdgcn_s_setprio(0);
            }
        }
        __syncthreads();
        buf ^= 1;
    }

    if (ck == 2) {
        const float inv_l = 1.0f / l_run;
        u16* orow = obuf + (rowbase + q) * 2048 + h * 128;
#pragma unroll
        for (int dt = 0; dt < 4; ++dt) {
#pragma unroll
            for (int rr = 0; rr < 4; ++rr) {
                int d0 = dt * 32 + rr * 8 + g * 4;
                int r0 = rr * 4;
                u32 w0 = pack_bf2(acc[dt][r0] * inv_l,     acc[dt][r0 + 1] * inv_l);
                u32 w1 = pack_bf2(acc[dt][r0 + 2] * inv_l, acc[dt][r0 + 3] * inv_l);
                *(u32*)(orow + d0)     = w0;
                *(u32*)(orow + d0 + 2) = w1;
            }
        }
    } else {
        const int slot = (((bh << 3) | (qt - 8)) << 1) + ck;
        const int qloc = w * 32 + ql;
        float* po = pout + (size_t)slot * 16384 + (size_t)qloc * 128;
#pragma unroll
        for (int dt = 0; dt < 4; ++dt) {
#pragma unroll
            for (int rr = 0; rr < 4; ++rr) {
                int d0 = dt * 32 + rr * 8 + g * 4;
                int r0 = rr * 4;
                float4 v4 = make_float4(acc[dt][r0], acc[dt][r0 + 1],
                                        acc[dt][r0 + 2], acc[dt][r0 + 3]);
                *(float4*)(po + d0) = v4;
            }
        }
        if (g == 0) {
            float2* pm = (float2*)pml + slot * 128 + qloc;
            *pm = make_float2(m_run, l_run);
        }
    }
}

// ---------------- merge the two KV-chunk partials (qt >= 8) -----------------
__global__ __launch_bounds__(256) void attn_merge(
    const float* __restrict__ pout, const float* __restrict__ pml,
    u16* __restrict__ obuf)
{
    const int bid = blockIdx.x;          // 256 = bh(32) x qto(8)
    const int bh = bid >> 3, qto = bid & 7;
    const int b = bh >> 4, h = bh & 15;
    const int tid = threadIdx.x;
    const int qloc = tid >> 1, half = (tid & 1) * 64;
    const int base = ((bh << 3) | qto) << 1;
    const float C2 = 0.08838834764831845f * 1.44269504088896341f;

    const float2 ml0 = ((const float2*)pml)[(base + 0) * 128 + qloc];
    const float2 ml1 = ((const float2*)pml)[(base + 1) * 128 + qloc];
    const float ms = fmaxf(ml0.x, ml1.x);
    const float w0 = exp2f((ml0.x - ms) * C2);
    const float w1 = exp2f((ml1.x - ms) * C2);
    const float inv = 1.0f / (ml0.y * w0 + ml1.y * w1);

    const float* p0 = pout + (size_t)(base + 0) * 16384 + (size_t)qloc * 128 + half;
    const float* p1 = pout + (size_t)(base + 1) * 16384 + (size_t)qloc * 128 + half;
    const int qrow = (8 + qto) * 128 + qloc;
    u16* orow = obuf + ((size_t)b * 2048 + qrow) * 2048 + h * 128 + half;
#pragma unroll
    for (int j = 0; j < 64; j += 4) {
        float4 a = *(const float4*)(p0 + j);
        float4 c = *(const float4*)(p1 + j);
        float o0 = (a.x * w0 + c.x * w1) * inv;
        float o1 = (a.y * w0 + c.y * w1) * inv;
        float o2 = (a.z * w0 + c.z * w1) * inv;
        float o3 = (a.w * w0 + c.w * w1) * inv;
        *(u32*)(orow + j)     = pack_bf2(o0, o1);
        *(u32*)(orow + j + 2) = pack_bf2(o2, o3);
    }
}

extern "C" void kernel_launch(void* const* d_in, const int* in_sizes, int n_in,
                              void* d_out, int out_size, void* d_ws, size_t ws_size,
                              hipStream_t stream) {
    (void)in_sizes; (void)n_in; (void)out_size; (void)ws_size;
    const float* x    = (const float*)d_in[0];
    const float* Wqkv = (const float*)d_in[1];
    const float* bqkv = (const float*)d_in[2];
    const float* Wout = (const float*)d_in[3];
    const float* bout = (const float*)d_in[4];

    char* ws = (char*)d_ws;
    u16* xb  = (u16*)ws;                        // [4096,2048] bf16, 16 MB
    u16* wqb = (u16*)(ws + (size_t)16777216);   // [6144,2048] bf16, 24 MB
    u16* qkv = (u16*)(ws + (size_t)41943040);   // [4096,6144] bf16, 48 MB
    u16* ob  = xb;   // attention out reuses xb (x dead after GEMM1)
    u16* vtb = wqb;  // V^T [32,128,2048] bf16 16 MB reuses wqb
    u16* wob = wqb;  // W_out bf16 reuses wqb again (vtb dead after attn)
    float* pml = (float*)(ws + (size_t)33554432);  // 512KB in wqb tail hole
    float* pO  = (float*)d_out;  // 32 MB f32 partials: d_out is free scratch
                                 // until gemm2 overwrites it

    cvt_f32_bf16<<<2048, 256, 0, stream>>>(x, xb, 8388608L / 8);
    cvt_f32_bf16<<<2048, 256, 0, stream>>>(Wqkv, wqb, 12582912L / 8);
    gemm_nt<1><<<1536, 256, 0, stream>>>(xb, wqb, bqkv, qkv, 2048, 6144, 5);
    transpose_v<<<2048, 256, 0, stream>>>(qkv, vtb);
    attn_fwd<<<768, 256, 0, stream>>>(qkv, vtb, ob, pO, pml);
    attn_merge<<<256, 256, 0, stream>>>(pO, pml, ob);
    cvt_f32_bf16<<<2048, 256, 0, stream>>>(Wout, wob, 4194304L / 8);
    gemm_nt<0><<<512, 256, 0, stream>>>(ob, wob, bout, d_out, 2048, 2048, 5);
}